// Round 6
// baseline (32293.744 us; speedup 1.0000x reference)
//
#include <hip/hip_runtime.h>

// 2-layer LSTM (B=4096, T=512, H=50) + FC head, fp32.
// R6 vs R5 (3.56 ms, VALU-issue-bound at ~2.7x the FMA floor):
//  - k-split 4 (was 8): block = 256 thr = 64 units x 4 ko (16 k each),
//    1 block/CU (LDS pin) -> 1 wave/SIMD -> 512-VGPR budget; weights 192 regs.
//  - reduction: 2 DPP quad hops only (ds_swizzle GONE -> bank-conflict ~0),
//    interleaved hop/select (144 ops vs 176), owner-finish (lane ko owns
//    batches 4g+ko).
//  - h LDS layout: k-group ko stored at column 20*ko (+4j) -> the 4 ko
//    b128 reads hit disjoint banks {0,20,8,28}+4j -> conflict-free.
//  - A-init via mul (no zero-init movs).

#define LOG2E 1.44269504088896340736f

template <int CTRL>
__device__ __forceinline__ float dppf(float v) {
  return __int_as_float(
      __builtin_amdgcn_mov_dpp(__float_as_int(v), CTRL, 0xf, 0xf, true));
}
template <int CTRL>
__device__ __forceinline__ void hop4(float4& a) {
  a.x += dppf<CTRL>(a.x); a.y += dppf<CTRL>(a.y);
  a.z += dppf<CTRL>(a.z); a.w += dppf<CTRL>(a.w);
}
__device__ __forceinline__ float4 sel4(bool c, const float4& a, const float4& b) {
  return make_float4(c ? a.x : b.x, c ? a.y : b.y, c ? a.z : b.z, c ? a.w : b.w);
}
__device__ __forceinline__ float sigm(float x) {
  return __builtin_amdgcn_rcpf(1.f + __builtin_amdgcn_exp2f(-LOG2E * x));
}
__device__ __forceinline__ float tanh_(float x) {
  return 1.f - 2.f * __builtin_amdgcn_rcpf(1.f + __builtin_amdgcn_exp2f(2.f * LOG2E * x));
}
__device__ __forceinline__ void fma4(float4& a, float s, const float4& w) {
  a.x += s * w.x; a.y += s * w.y; a.z += s * w.z; a.w += s * w.w;
}
__device__ __forceinline__ float4 mul4(float s, const float4& w) {
  return make_float4(s * w.x, s * w.y, s * w.z, s * w.w);
}

__global__ __launch_bounds__(256)
void lstm2_kernel(
    const float* __restrict__ x,
    const float* __restrict__ Wih0, const float* __restrict__ Whh0,
    const float* __restrict__ bih0, const float* __restrict__ bhh0,
    const float* __restrict__ Wih1, const float* __restrict__ Whh1,
    const float* __restrict__ bih1, const float* __restrict__ bhh1,
    const float* __restrict__ fcW, const float* __restrict__ fcb,
    float* __restrict__ out) {
  const int tid = threadIdx.x;
  const int n  = tid >> 2;  // padded unit 0..63 (>=50 dummy)
  const int ko = tid & 3;   // k-quarter (16 k each)
  const int bbase = blockIdx.x * 16;

  // h layout: [parity][batch][80]: k-group g at column 20*g + (k&15).
  __shared__ float h0s[2][16][80];
  __shared__ float h1s[2][16][80];
  __shared__ float xs[16][68];     // x chunk, stride 68 (16B-aligned rows)
  __shared__ float ldspad[16384];  // occupancy pin: 64 KB -> 1 block/CU

  ((volatile float*)ldspad)[tid] = 0.f;  // keep pad alive (never read)

  for (int i = tid; i < 2 * 16 * 80; i += 256) {
    ((float*)h0s)[i] = 0.f;
    ((float*)h1s)[i] = 0.f;
  }

  // ---- per-lane weight slices: w*[j][kk] = float4 over gates {i,f,g,o}
  //      at k = 16*ko + 4*j + kk,  j in [0,4)
  float4 w0g[4][4], w1ig[4][4], w1hg[4][4];
  const bool nv = (n < 50);
#pragma unroll
  for (int j = 0; j < 4; ++j) {
#pragma unroll
    for (int kk = 0; kk < 4; ++kk) {
      const int k = 16 * ko + 4 * j + kk;
      const bool kv = nv && (k < 50);
      float4 a, b, c;
      a.x = kv ? Whh0[(0 * 50 + n) * 50 + k] : 0.f;
      a.y = kv ? Whh0[(1 * 50 + n) * 50 + k] : 0.f;
      a.z = kv ? Whh0[(2 * 50 + n) * 50 + k] : 0.f;
      a.w = kv ? Whh0[(3 * 50 + n) * 50 + k] : 0.f;
      b.x = kv ? Wih1[(0 * 50 + n) * 50 + k] : 0.f;
      b.y = kv ? Wih1[(1 * 50 + n) * 50 + k] : 0.f;
      b.z = kv ? Wih1[(2 * 50 + n) * 50 + k] : 0.f;
      b.w = kv ? Wih1[(3 * 50 + n) * 50 + k] : 0.f;
      c.x = kv ? Whh1[(0 * 50 + n) * 50 + k] : 0.f;
      c.y = kv ? Whh1[(1 * 50 + n) * 50 + k] : 0.f;
      c.z = kv ? Whh1[(2 * 50 + n) * 50 + k] : 0.f;
      c.w = kv ? Whh1[(3 * 50 + n) * 50 + k] : 0.f;
      w0g[j][kk] = a; w1ig[j][kk] = b; w1hg[j][kk] = c;
    }
  }
  float4 bb0, bb1, wx0;
  bb0.x = nv ? (bih0[0 * 50 + n] + bhh0[0 * 50 + n]) : 0.f;
  bb0.y = nv ? (bih0[1 * 50 + n] + bhh0[1 * 50 + n]) : 0.f;
  bb0.z = nv ? (bih0[2 * 50 + n] + bhh0[2 * 50 + n]) : 0.f;
  bb0.w = nv ? (bih0[3 * 50 + n] + bhh0[3 * 50 + n]) : 0.f;
  bb1.x = nv ? (bih1[0 * 50 + n] + bhh1[0 * 50 + n]) : 0.f;
  bb1.y = nv ? (bih1[1 * 50 + n] + bhh1[1 * 50 + n]) : 0.f;
  bb1.z = nv ? (bih1[2 * 50 + n] + bhh1[2 * 50 + n]) : 0.f;
  bb1.w = nv ? (bih1[3 * 50 + n] + bhh1[3 * 50 + n]) : 0.f;
  wx0.x = nv ? Wih0[0 * 50 + n] : 0.f;
  wx0.y = nv ? Wih0[1 * 50 + n] : 0.f;
  wx0.z = nv ? Wih0[2 * 50 + n] : 0.f;
  wx0.w = nv ? Wih0[3 * 50 + n] : 0.f;

  // lane ko owns batches 4g+ko (g=0..3) of each layer
  float c0own[4] = {0.f, 0.f, 0.f, 0.f};
  float c1own[4] = {0.f, 0.f, 0.f, 0.f};
  const bool s0 = (ko & 1) != 0, s1 = (ko & 2) != 0;
  const int nOff = 20 * (n >> 4) + (n & 15);  // writer column
  const int kcol = 20 * ko;                   // reader k-group column

  for (int t = 0; t < 512; ++t) {
    if ((t & 63) == 0) {  // stage next 64 timesteps of x
      __syncthreads();
      const int sb = tid >> 4, st = (tid & 15) << 2;
      *(float4*)&xs[sb][st] =
          *(const float4*)&x[(size_t)(bbase + sb) * 512 + t + st];
      __syncthreads();
    }
    const int rp = (t + 1) & 1;
    const int wp = t & 1;
    const int tm = t & 63;
    const float* h0r = &h0s[rp][0][0];
    float*       h0w = &h0s[wp][0][0];
    const float* h1r = &h1s[rp][0][0];
    float*       h1w = &h1s[wp][0][0];

    // ================= layer 0 =================
    float4 A[16];
#pragma unroll
    for (int b = 0; b < 16; ++b) {  // j=0: init via mul
      const float4 hf = *(const float4*)&h0r[b * 80 + kcol];
      A[b] = mul4(hf.x, w0g[0][0]);
      fma4(A[b], hf.y, w0g[0][1]);
      fma4(A[b], hf.z, w0g[0][2]);
      fma4(A[b], hf.w, w0g[0][3]);
    }
#pragma unroll
    for (int j = 1; j < 4; ++j) {
#pragma unroll
      for (int b = 0; b < 16; ++b) {
        const float4 hf = *(const float4*)&h0r[b * 80 + kcol + 4 * j];
        fma4(A[b], hf.x, w0g[j][0]);
        fma4(A[b], hf.y, w0g[j][1]);
        fma4(A[b], hf.z, w0g[j][2]);
        fma4(A[b], hf.w, w0g[j][3]);
      }
    }
    // reduce over 4 ko lanes: hop, sel, hop; lane ko ends with b=4g+ko sums
#pragma unroll
    for (int b = 0; b < 16; ++b) hop4<0xB1>(A[b]);
    {
      float4 V[8];
#pragma unroll
      for (int j = 0; j < 8; ++j) V[j] = sel4(s0, A[2 * j + 1], A[2 * j]);
#pragma unroll
      for (int j = 0; j < 8; ++j) hop4<0x4E>(V[j]);
#pragma unroll
      for (int g = 0; g < 4; ++g) {
        const float4 D = sel4(s1, V[2 * g + 1], V[2 * g]);
        const int b = 4 * g + ko;
        const float xv = xs[b][tm];
        const float gi = sigm(D.x + bb0.x + xv * wx0.x);
        const float gf = sigm(D.y + bb0.y + xv * wx0.y);
        const float gg = tanh_(D.z + bb0.z + xv * wx0.z);
        const float go = sigm(D.w + bb0.w + xv * wx0.w);
        const float c = gf * c0own[g] + gi * gg;
        c0own[g] = c;
        h0w[b * 80 + nOff] = go * tanh_(c);
      }
    }
    __syncthreads();  // h0[t] ready

    // ================= layer 1 =================
#pragma unroll
    for (int b = 0; b < 16; ++b) {  // j=0: init via mul
      const float4 hf0 = *(const float4*)&h0w[b * 80 + kcol];
      A[b] = mul4(hf0.x, w1ig[0][0]);
      fma4(A[b], hf0.y, w1ig[0][1]);
      fma4(A[b], hf0.z, w1ig[0][2]);
      fma4(A[b], hf0.w, w1ig[0][3]);
      const float4 hf1 = *(const float4*)&h1r[b * 80 + kcol];
      fma4(A[b], hf1.x, w1hg[0][0]);
      fma4(A[b], hf1.y, w1hg[0][1]);
      fma4(A[b], hf1.z, w1hg[0][2]);
      fma4(A[b], hf1.w, w1hg[0][3]);
    }
#pragma unroll
    for (int j = 1; j < 4; ++j) {
#pragma unroll
      for (int b = 0; b < 16; ++b) {
        const float4 hf0 = *(const float4*)&h0w[b * 80 + kcol + 4 * j];
        const float4 hf1 = *(const float4*)&h1r[b * 80 + kcol + 4 * j];
        fma4(A[b], hf0.x, w1ig[j][0]);
        fma4(A[b], hf0.y, w1ig[j][1]);
        fma4(A[b], hf0.z, w1ig[j][2]);
        fma4(A[b], hf0.w, w1ig[j][3]);
        fma4(A[b], hf1.x, w1hg[j][0]);
        fma4(A[b], hf1.y, w1hg[j][1]);
        fma4(A[b], hf1.z, w1hg[j][2]);
        fma4(A[b], hf1.w, w1hg[j][3]);
      }
    }
#pragma unroll
    for (int b = 0; b < 16; ++b) hop4<0xB1>(A[b]);
    {
      float4 V[8];
#pragma unroll
      for (int j = 0; j < 8; ++j) V[j] = sel4(s0, A[2 * j + 1], A[2 * j]);
#pragma unroll
      for (int j = 0; j < 8; ++j) hop4<0x4E>(V[j]);
#pragma unroll
      for (int g = 0; g < 4; ++g) {
        const float4 D = sel4(s1, V[2 * g + 1], V[2 * g]);
        const int b = 4 * g + ko;
        const float gi = sigm(D.x + bb1.x);
        const float gf = sigm(D.y + bb1.y);
        const float gg = tanh_(D.z + bb1.z);
        const float go = sigm(D.w + bb1.w);
        const float c = gf * c1own[g] + gi * gg;
        c1own[g] = c;
        h1w[b * 80 + nOff] = go * tanh_(c);
      }
    }
    __syncthreads();  // h1[t] ready; also guards next step's WAR
  }

  // ---- FC head: out[b] = fc_b + sum_j fcW[j] * h1_last[b][j] ----
  if (tid < 16) {
    float s = fcb[0];
    for (int j = 0; j < 50; ++j)
      s += fcW[j] * h1s[1][tid][20 * (j >> 4) + (j & 15)];  // t=511 -> parity 1
    out[bbase + tid] = s;
  }
}

extern "C" void kernel_launch(void* const* d_in, const int* in_sizes, int n_in,
                              void* d_out, int out_size, void* d_ws, size_t ws_size,
                              hipStream_t stream) {
  const float* x    = (const float*)d_in[0];
  const float* Wih0 = (const float*)d_in[1];
  const float* Whh0 = (const float*)d_in[2];
  const float* bih0 = (const float*)d_in[3];
  const float* bhh0 = (const float*)d_in[4];
  const float* Wih1 = (const float*)d_in[5];
  const float* Whh1 = (const float*)d_in[6];
  const float* bih1 = (const float*)d_in[7];
  const float* bhh1 = (const float*)d_in[8];
  const float* fcW  = (const float*)d_in[9];
  const float* fcb  = (const float*)d_in[10];
  float* out = (float*)d_out;

  const int B = out_size;          // 4096
  const int blocks = B / 16;       // 256
  lstm2_kernel<<<dim3(blocks), dim3(256), 0, stream>>>(
      x, Wih0, Whh0, bih0, bhh0, Wih1, Whh1, bih1, bhh1, fcW, fcb, out);
}

// Round 7
// 7501.333 us; speedup vs baseline: 4.3051x; 4.3051x over previous
//
#include <hip/hip_runtime.h>

// 2-layer LSTM (B=4096, T=512, H=50) + FC head, fp32.
// R7 = R6's math (correct, 4-way k-split) with register residency FORCED:
//  - R6 failure: compiler promoted float4 A[16] to LDS (+64KB LDS, 1.7e10
//    bank conflicts, VALUBusy 7%) and shorted weights (VGPR 184 < 192).
//  - Fix: NO local arrays at all. A0..A15, V0..V7, all 48 weight float4s,
//    c-states are individually named values (macro-expanded) -> SSA, not
//    allocas -> cannot be promoted or scratch-spilled wholesale.
//  - LDS pad grown to 120832 B (total 145664 B): pins 1 block/CU (512-VGPR
//    budget) AND leaves <18KB free so nothing promotable would fit anyway.
//  - amdgpu_waves_per_eu(1,1): RA may use up to 512 regs, no occupancy chase.
// Block = 256 thr = 64 units x 4 ko (16 k each); 16 batches/block; 256 blocks.
// Reduce over ko: DPP quad_perm xor1 -> select -> xor2 -> select (owner-finish).

#define LOG2E 1.44269504088896340736f

template <int CTRL>
__device__ __forceinline__ float dppf(float v) {
  return __int_as_float(
      __builtin_amdgcn_mov_dpp(__float_as_int(v), CTRL, 0xf, 0xf, true));
}
template <int CTRL>
__device__ __forceinline__ void hop4(float4& a) {
  a.x += dppf<CTRL>(a.x); a.y += dppf<CTRL>(a.y);
  a.z += dppf<CTRL>(a.z); a.w += dppf<CTRL>(a.w);
}
__device__ __forceinline__ float4 sel4(bool c, const float4& a, const float4& b) {
  return make_float4(c ? a.x : b.x, c ? a.y : b.y, c ? a.z : b.z, c ? a.w : b.w);
}
__device__ __forceinline__ float sigm(float x) {
  return __builtin_amdgcn_rcpf(1.f + __builtin_amdgcn_exp2f(-LOG2E * x));
}
__device__ __forceinline__ float tanh_(float x) {
  return 1.f - 2.f * __builtin_amdgcn_rcpf(1.f + __builtin_amdgcn_exp2f(2.f * LOG2E * x));
}
__device__ __forceinline__ void fma4(float4& a, float s, const float4& w) {
  a.x += s * w.x; a.y += s * w.y; a.z += s * w.z; a.w += s * w.w;
}
__device__ __forceinline__ float4 mul4(float s, const float4& w) {
  return make_float4(s * w.x, s * w.y, s * w.z, s * w.w);
}
__device__ __forceinline__ float4 ldw4(const float* __restrict__ W, int n, int k,
                                       bool v) {
  return make_float4(v ? W[(0 * 50 + n) * 50 + k] : 0.f,
                     v ? W[(1 * 50 + n) * 50 + k] : 0.f,
                     v ? W[(2 * 50 + n) * 50 + k] : 0.f,
                     v ? W[(3 * 50 + n) * 50 + k] : 0.f);
}

#define WJK_LIST(X) X(0,0) X(0,1) X(0,2) X(0,3) \
                    X(1,0) X(1,1) X(1,2) X(1,3) \
                    X(2,0) X(2,1) X(2,2) X(2,3) \
                    X(3,0) X(3,1) X(3,2) X(3,3)
#define B_LIST(X) X(0) X(1) X(2) X(3) X(4) X(5) X(6) X(7) \
                  X(8) X(9) X(10) X(11) X(12) X(13) X(14) X(15)

__global__ __attribute__((amdgpu_flat_work_group_size(256, 256)))
__attribute__((amdgpu_waves_per_eu(1, 1)))
void lstm2_kernel(
    const float* __restrict__ x,
    const float* __restrict__ Wih0, const float* __restrict__ Whh0,
    const float* __restrict__ bih0, const float* __restrict__ bhh0,
    const float* __restrict__ Wih1, const float* __restrict__ Whh1,
    const float* __restrict__ bih1, const float* __restrict__ bhh1,
    const float* __restrict__ fcW, const float* __restrict__ fcb,
    float* __restrict__ out) {
  const int tid = threadIdx.x;
  const int n  = tid >> 2;  // padded unit 0..63 (>=50 dummy)
  const int ko = tid & 3;   // k-quarter (16 k each)
  const int bbase = blockIdx.x * 16;

  // h layout: [parity][batch][80]: k-group g at column 20*g + (k&15).
  __shared__ float h0s[2][16][80];
  __shared__ float h1s[2][16][80];
  __shared__ float xs[16][68];      // x chunk, stride 68 (16B-aligned rows)
  __shared__ float ldspad[30208];   // 120832 B pin -> total 145664 B, 1 blk/CU

  ((volatile float*)ldspad)[tid] = 0.f;  // keep pad alive (never read)

  for (int i = tid; i < 2 * 16 * 80; i += 256) {
    ((float*)h0s)[i] = 0.f;
    ((float*)h1s)[i] = 0.f;
  }

  // ---- 48 named weight float4s: w0/wi/wh _j_kk over gates {i,f,g,o}
  //      at k = 16*ko + 4*j + kk
  const bool nv = (n < 50);
#define DECLW(j,kk) float4 w0_##j##_##kk, wi_##j##_##kk, wh_##j##_##kk;
  WJK_LIST(DECLW)
#define LOADW(j,kk) { const int k = 16 * ko + 4 * (j) + (kk); \
    const bool kv = nv && (k < 50); \
    w0_##j##_##kk = ldw4(Whh0, n, k, kv); \
    wi_##j##_##kk = ldw4(Wih1, n, k, kv); \
    wh_##j##_##kk = ldw4(Whh1, n, k, kv); }
  WJK_LIST(LOADW)

  float4 bb0, bb1, wx0;
  bb0.x = nv ? (bih0[0 * 50 + n] + bhh0[0 * 50 + n]) : 0.f;
  bb0.y = nv ? (bih0[1 * 50 + n] + bhh0[1 * 50 + n]) : 0.f;
  bb0.z = nv ? (bih0[2 * 50 + n] + bhh0[2 * 50 + n]) : 0.f;
  bb0.w = nv ? (bih0[3 * 50 + n] + bhh0[3 * 50 + n]) : 0.f;
  bb1.x = nv ? (bih1[0 * 50 + n] + bhh1[0 * 50 + n]) : 0.f;
  bb1.y = nv ? (bih1[1 * 50 + n] + bhh1[1 * 50 + n]) : 0.f;
  bb1.z = nv ? (bih1[2 * 50 + n] + bhh1[2 * 50 + n]) : 0.f;
  bb1.w = nv ? (bih1[3 * 50 + n] + bhh1[3 * 50 + n]) : 0.f;
  wx0.x = nv ? Wih0[0 * 50 + n] : 0.f;
  wx0.y = nv ? Wih0[1 * 50 + n] : 0.f;
  wx0.z = nv ? Wih0[2 * 50 + n] : 0.f;
  wx0.w = nv ? Wih0[3 * 50 + n] : 0.f;

  // lane ko owns batches 4g+ko (g=0..3); named c-states
  float c0_0 = 0.f, c0_1 = 0.f, c0_2 = 0.f, c0_3 = 0.f;
  float c1_0 = 0.f, c1_1 = 0.f, c1_2 = 0.f, c1_3 = 0.f;
  const bool s0 = (ko & 1) != 0, s1 = (ko & 2) != 0;
  const int nOff = 20 * (n >> 4) + (n & 15);  // writer column
  const int kcol = 20 * ko;                   // reader k-group column

  for (int t = 0; t < 512; ++t) {
    if ((t & 63) == 0) {  // stage next 64 timesteps of x
      __syncthreads();
      const int sb = tid >> 4, st = (tid & 15) << 2;
      *(float4*)&xs[sb][st] =
          *(const float4*)&x[(size_t)(bbase + sb) * 512 + t + st];
      __syncthreads();
    }
    const int rp = (t + 1) & 1;
    const int wp = t & 1;
    const int tm = t & 63;
    const float* h0r = &h0s[rp][0][0];
    float*       h0w = &h0s[wp][0][0];
    const float* h1r = &h1s[rp][0][0];
    float*       h1w = &h1s[wp][0][0];

    // ================= layer 0 =================
    {
#define L0_INIT(b) const float4 hf##b = *(const float4*)(h0r + (b) * 80 + kcol); \
      float4 A##b = mul4(hf##b.x, w0_0_0); \
      fma4(A##b, hf##b.y, w0_0_1); fma4(A##b, hf##b.z, w0_0_2); \
      fma4(A##b, hf##b.w, w0_0_3);
      B_LIST(L0_INIT)
#define L0_J(b,j) { const float4 hf = *(const float4*)(h0r + (b) * 80 + kcol + 4 * (j)); \
      fma4(A##b, hf.x, w0_##j##_0); fma4(A##b, hf.y, w0_##j##_1); \
      fma4(A##b, hf.z, w0_##j##_2); fma4(A##b, hf.w, w0_##j##_3); }
#define L0_J1(b) L0_J(b,1)
#define L0_J2(b) L0_J(b,2)
#define L0_J3(b) L0_J(b,3)
      B_LIST(L0_J1)
      B_LIST(L0_J2)
      B_LIST(L0_J3)
#define HOPA(b) hop4<0xB1>(A##b);
      B_LIST(HOPA)
      float4 V0 = sel4(s0, A1, A0),   V1 = sel4(s0, A3, A2);
      float4 V2 = sel4(s0, A5, A4),   V3 = sel4(s0, A7, A6);
      float4 V4 = sel4(s0, A9, A8),   V5 = sel4(s0, A11, A10);
      float4 V6 = sel4(s0, A13, A12), V7 = sel4(s0, A15, A14);
      hop4<0x4E>(V0); hop4<0x4E>(V1); hop4<0x4E>(V2); hop4<0x4E>(V3);
      hop4<0x4E>(V4); hop4<0x4E>(V5); hop4<0x4E>(V6); hop4<0x4E>(V7);
#define FIN0(g, Vlo, Vhi, cvar) { \
      const float4 D = sel4(s1, Vhi, Vlo); \
      const int b = 4 * (g) + ko; \
      const float xv = xs[b][tm]; \
      const float gi = sigm(D.x + bb0.x + xv * wx0.x); \
      const float gf = sigm(D.y + bb0.y + xv * wx0.y); \
      const float gg = tanh_(D.z + bb0.z + xv * wx0.z); \
      const float go = sigm(D.w + bb0.w + xv * wx0.w); \
      const float c = gf * cvar + gi * gg; cvar = c; \
      h0w[b * 80 + nOff] = go * tanh_(c); }
      FIN0(0, V0, V1, c0_0)
      FIN0(1, V2, V3, c0_1)
      FIN0(2, V4, V5, c0_2)
      FIN0(3, V6, V7, c0_3)
    }
    __syncthreads();  // h0[t] ready

    // ================= layer 1 =================
    {
#define L1_INIT(b) float4 A##b; \
      { const float4 hf0 = *(const float4*)(h0w + (b) * 80 + kcol); \
        A##b = mul4(hf0.x, wi_0_0); \
        fma4(A##b, hf0.y, wi_0_1); fma4(A##b, hf0.z, wi_0_2); \
        fma4(A##b, hf0.w, wi_0_3); \
        const float4 hf1 = *(const float4*)(h1r + (b) * 80 + kcol); \
        fma4(A##b, hf1.x, wh_0_0); fma4(A##b, hf1.y, wh_0_1); \
        fma4(A##b, hf1.z, wh_0_2); fma4(A##b, hf1.w, wh_0_3); }
      B_LIST(L1_INIT)
#define L1_J(b,j) { const float4 hf0 = *(const float4*)(h0w + (b) * 80 + kcol + 4 * (j)); \
      fma4(A##b, hf0.x, wi_##j##_0); fma4(A##b, hf0.y, wi_##j##_1); \
      fma4(A##b, hf0.z, wi_##j##_2); fma4(A##b, hf0.w, wi_##j##_3); \
      const float4 hf1 = *(const float4*)(h1r + (b) * 80 + kcol + 4 * (j)); \
      fma4(A##b, hf1.x, wh_##j##_0); fma4(A##b, hf1.y, wh_##j##_1); \
      fma4(A##b, hf1.z, wh_##j##_2); fma4(A##b, hf1.w, wh_##j##_3); }
#define L1_J1(b) L1_J(b,1)
#define L1_J2(b) L1_J(b,2)
#define L1_J3(b) L1_J(b,3)
      B_LIST(L1_J1)
      B_LIST(L1_J2)
      B_LIST(L1_J3)
      B_LIST(HOPA)
      float4 V0 = sel4(s0, A1, A0),   V1 = sel4(s0, A3, A2);
      float4 V2 = sel4(s0, A5, A4),   V3 = sel4(s0, A7, A6);
      float4 V4 = sel4(s0, A9, A8),   V5 = sel4(s0, A11, A10);
      float4 V6 = sel4(s0, A13, A12), V7 = sel4(s0, A15, A14);
      hop4<0x4E>(V0); hop4<0x4E>(V1); hop4<0x4E>(V2); hop4<0x4E>(V3);
      hop4<0x4E>(V4); hop4<0x4E>(V5); hop4<0x4E>(V6); hop4<0x4E>(V7);
#define FIN1(g, Vlo, Vhi, cvar) { \
      const float4 D = sel4(s1, Vhi, Vlo); \
      const int b = 4 * (g) + ko; \
      const float gi = sigm(D.x + bb1.x); \
      const float gf = sigm(D.y + bb1.y); \
      const float gg = tanh_(D.z + bb1.z); \
      const float go = sigm(D.w + bb1.w); \
      const float c = gf * cvar + gi * gg; cvar = c; \
      h1w[b * 80 + nOff] = go * tanh_(c); }
      FIN1(0, V0, V1, c1_0)
      FIN1(1, V2, V3, c1_1)
      FIN1(2, V4, V5, c1_2)
      FIN1(3, V6, V7, c1_3)
    }
    __syncthreads();  // h1[t] ready; also guards next step's WAR
  }

  // ---- FC head: out[b] = fc_b + sum_j fcW[j] * h1_last[b][j] ----
  if (tid < 16) {
    float s = fcb[0];
    for (int j = 0; j < 50; ++j)
      s += fcW[j] * h1s[1][tid][20 * (j >> 4) + (j & 15)];  // t=511 -> parity 1
    out[bbase + tid] = s;
  }
}

extern "C" void kernel_launch(void* const* d_in, const int* in_sizes, int n_in,
                              void* d_out, int out_size, void* d_ws, size_t ws_size,
                              hipStream_t stream) {
  const float* x    = (const float*)d_in[0];
  const float* Wih0 = (const float*)d_in[1];
  const float* Whh0 = (const float*)d_in[2];
  const float* bih0 = (const float*)d_in[3];
  const float* bhh0 = (const float*)d_in[4];
  const float* Wih1 = (const float*)d_in[5];
  const float* Whh1 = (const float*)d_in[6];
  const float* bih1 = (const float*)d_in[7];
  const float* bhh1 = (const float*)d_in[8];
  const float* fcW  = (const float*)d_in[9];
  const float* fcb  = (const float*)d_in[10];
  float* out = (float*)d_out;

  const int B = out_size;          // 4096
  const int blocks = B / 16;       // 256
  lstm2_kernel<<<dim3(blocks), dim3(256), 0, stream>>>(
      x, Wih0, Whh0, bih0, bhh0, Wih1, Whh1, bih1, bhh1, fcW, fcb, out);
}

// Round 8
// 1124.707 us; speedup vs baseline: 28.7130x; 6.6696x over previous
//
#include <hip/hip_runtime.h>

// 2-layer LSTM (B=4096, T=512, H=50) + FC head.
// R8: matmuls moved to MFMA (mfma_f32_16x16x32_bf16) with bf16 hi/lo pair
// splitting (3 mfma per logical product; lo*lo dropped, rel err ~2^-18).
// Ledger: fp32-VALU structure (R5) saturated VALU issue at ~10x the FMA
// floor; R7 showed arch-VGPR cap is 256 (rest is AGPR w/ copy cost).
// Structure: 256 blocks x 16 batches. Block = 512 thr = 8 waves.
// Rows of the gate matrix are UNIT-MAJOR interleaved: row r = 4*unit + gate,
// so each 16x16 N-tile = 4 units x 4 gates and the c-update's {i,f,g,o}
// live in one lane-quad -> DPP quad-broadcasts, no cross-wave exchange.
// Wave w owns N-tiles 2w,2w+1 = units 8w..8w+7 (>=50 padded to zero).
// h kept in LDS as separate bf16 hi/lo planes [batch][72] so A-fragments
// are plain ds_read_b64 pairs. c-state stays fp32 in registers.
// A/B fragment layout (gfx950): row/col = lane&15, k = 16*(e>>2)+4*(lane>>4)+(e&3).
// C/D: col = lane&15, row = 4*(lane>>4) + reg  [m89-verified].

typedef __attribute__((ext_vector_type(8))) short short8;
typedef __attribute__((ext_vector_type(4))) float f32x4;

#define LOG2E 1.44269504088896340736f

__device__ __forceinline__ unsigned short bf16_rne(float f) {
  unsigned int u = __float_as_uint(f);
  u += 0x7FFFu + ((u >> 16) & 1u);
  return (unsigned short)(u >> 16);
}
__device__ __forceinline__ float bf16f(unsigned short h) {
  return __uint_as_float(((unsigned int)h) << 16);
}

template <int CTRL>
__device__ __forceinline__ float qbc(float v) {  // quad broadcast via DPP
  return __int_as_float(
      __builtin_amdgcn_mov_dpp(__float_as_int(v), CTRL, 0xf, 0xf, true));
}
__device__ __forceinline__ float rcp_(float x) { return __builtin_amdgcn_rcpf(x); }
__device__ __forceinline__ float exp2_(float x) { return __builtin_amdgcn_exp2f(x); }
__device__ __forceinline__ float tanh_(float x) {
  return 1.f - 2.f * rcp_(1.f + exp2_(2.f * LOG2E * x));
}

__device__ __forceinline__ f32x4 mfma16(short8 a, short8 b, f32x4 c) {
  return __builtin_amdgcn_mfma_f32_16x16x32_bf16(a, b, c, 0, 0, 0);
}

union ABu { struct { uint2 a, b; } u; short8 v; };

// two 8B LDS reads -> one A/B fragment (elems 0-3 from p0, 4-7 from p1)
__device__ __forceinline__ short8 rdfrag(const unsigned short* p0,
                                         const unsigned short* p1) {
  ABu t;
  t.u.a = *(const uint2*)p0;
  t.u.b = *(const uint2*)p1;
  return t.v;
}

// Load one B-fragment (hi & lo) of W (50x50 logical, gate-major rows) for
// column (n,gate), k = kbase + 16*(e>>2) + 4*lg + (e&3).
__device__ __forceinline__ void loadB(const float* __restrict__ W, int n,
                                      int gate, int kbase, int lg,
                                      short8& h8, short8& l8) {
#pragma unroll
  for (int e = 0; e < 8; ++e) {
    const int k = kbase + 16 * (e >> 2) + 4 * lg + (e & 3);
    const bool v = (n < 50) && (k < 50);
    const float w = v ? W[(gate * 50 + n) * 50 + k] : 0.f;
    const unsigned short hb = bf16_rne(w);
    const unsigned short lb = bf16_rne(w - bf16f(hb));
    h8[e] = (short)hb;
    l8[e] = (short)lb;
  }
}

__global__ __launch_bounds__(512) void lstm2_kernel(
    const float* __restrict__ x,
    const float* __restrict__ Wih0, const float* __restrict__ Whh0,
    const float* __restrict__ bih0, const float* __restrict__ bhh0,
    const float* __restrict__ Wih1, const float* __restrict__ Whh1,
    const float* __restrict__ bih1, const float* __restrict__ bhh1,
    const float* __restrict__ fcW, const float* __restrict__ fcb,
    float* __restrict__ out) {
  const int tid = threadIdx.x;
  const int lane = tid & 63;
  const int wv = tid >> 6;        // wave 0..7
  const int lg = lane >> 4;       // lane-group 0..3 (k-slices / batch-groups)
  const int l15 = lane & 15;
  const int gate = lane & 3;      // gate this lane's column carries
  const int bbase = blockIdx.x * 16;

  __shared__ unsigned short H0h[2][16][72], H0l[2][16][72];
  __shared__ unsigned short H1h[2][16][72], H1l[2][16][72];
  __shared__ float xs[16][68];
  __shared__ float ldspad[15360];  // 60 KB pin -> total ~84 KB -> 1 block/CU

  ((volatile float*)ldspad)[tid] = 0.f;  // keep pad alive

  for (int i = tid; i < 2 * 16 * 72; i += 512) {
    ((unsigned short*)H0h)[i] = 0; ((unsigned short*)H0l)[i] = 0;
    ((unsigned short*)H1h)[i] = 0; ((unsigned short*)H1l)[i] = 0;
  }

  // ---- B-fragments (registers; ~96 VGPRs) ----
  const int u_T0 = 4 * (2 * wv + 0) + (l15 >> 2);  // this lane's unit, tile 0
  const int u_T1 = 4 * (2 * wv + 1) + (l15 >> 2);  // tile 1

  short8 W0h0_T0, W0l0_T0, W0h1_T0, W0l1_T0;   // Whh0 kt0,kt1
  short8 WIh0_T0, WIl0_T0, WIh1_T0, WIl1_T0;   // Wih1 kt0,kt1
  short8 WHh0_T0, WHl0_T0, WHh1_T0, WHl1_T0;   // Whh1 kt2,kt3 (k-64)
  short8 W0h0_T1, W0l0_T1, W0h1_T1, W0l1_T1;
  short8 WIh0_T1, WIl0_T1, WIh1_T1, WIl1_T1;
  short8 WHh0_T1, WHl0_T1, WHh1_T1, WHl1_T1;

  loadB(Whh0, u_T0, gate, 0,  lg, W0h0_T0, W0l0_T0);
  loadB(Whh0, u_T0, gate, 32, lg, W0h1_T0, W0l1_T0);
  loadB(Wih1, u_T0, gate, 0,  lg, WIh0_T0, WIl0_T0);
  loadB(Wih1, u_T0, gate, 32, lg, WIh1_T0, WIl1_T0);
  loadB(Whh1, u_T0, gate, 0,  lg, WHh0_T0, WHl0_T0);
  loadB(Whh1, u_T0, gate, 32, lg, WHh1_T0, WHl1_T0);
  loadB(Whh0, u_T1, gate, 0,  lg, W0h0_T1, W0l0_T1);
  loadB(Whh0, u_T1, gate, 32, lg, W0h1_T1, W0l1_T1);
  loadB(Wih1, u_T1, gate, 0,  lg, WIh0_T1, WIl0_T1);
  loadB(Wih1, u_T1, gate, 32, lg, WIh1_T1, WIl1_T1);
  loadB(Whh1, u_T1, gate, 0,  lg, WHh0_T1, WHl0_T1);
  loadB(Whh1, u_T1, gate, 32, lg, WHh1_T1, WHl1_T1);

  const bool v_T0 = (u_T0 < 50), v_T1 = (u_T1 < 50);
  const float bias0_T0 = v_T0 ? (bih0[gate * 50 + u_T0] + bhh0[gate * 50 + u_T0]) : 0.f;
  const float bias0_T1 = v_T1 ? (bih0[gate * 50 + u_T1] + bhh0[gate * 50 + u_T1]) : 0.f;
  const float bias1_T0 = v_T0 ? (bih1[gate * 50 + u_T0] + bhh1[gate * 50 + u_T0]) : 0.f;
  const float bias1_T1 = v_T1 ? (bih1[gate * 50 + u_T1] + bhh1[gate * 50 + u_T1]) : 0.f;
  const float wx_T0 = v_T0 ? Wih0[gate * 50 + u_T0] : 0.f;
  const float wx_T1 = v_T1 ? Wih0[gate * 50 + u_T1] : 0.f;

  // branchless sigmoid/tanh: act = cA + cB * rcp(1 + exp2(cC*x))
  const bool isg = (gate == 2);
  const float cA = isg ? 1.f : 0.f;
  const float cB = isg ? -2.f : 1.f;
  const float cC = isg ? (2.f * LOG2E) : (-LOG2E);
  const bool gs0 = (gate & 1) != 0, gs1 = (gate & 2) != 0;

  // c-state (fp32, duplicated across the quad -> consistent)
  float c0_T0_0 = 0.f, c0_T0_1 = 0.f, c0_T0_2 = 0.f, c0_T0_3 = 0.f;
  float c0_T1_0 = 0.f, c0_T1_1 = 0.f, c0_T1_2 = 0.f, c0_T1_3 = 0.f;
  float c1_T0_0 = 0.f, c1_T0_1 = 0.f, c1_T0_2 = 0.f, c1_T0_3 = 0.f;
  float c1_T1_0 = 0.f, c1_T1_1 = 0.f, c1_T1_2 = 0.f, c1_T1_3 = 0.f;

  const int arow = l15;       // A-fragment batch row
  const int k0a = 4 * lg;     // A-fragment k base within a 32-k tile
  const int wb = 4 * lg + gate;  // batch this lane writes (C row 4*lg + r, r=gate)

  // per-r finish: broadcast {i,f,g,o} across the quad, update c, compute h;
  // lane writes batch r==gate's h (hi/lo bf16) to LDS.
#define FIN(ACC, BIAS, X0, X1, X2, X3, C0v, C1v, C2v, C3v, PH, PL, WN)      \
  {                                                                          \
    float h0_, h1_, h2_, h3_;                                                \
    { const float pre = ACC[0] + BIAS + (X0);                                \
      const float a = cA + cB * rcp_(1.f + exp2_(cC * pre));                 \
      const float i_ = qbc<0x00>(a), f_ = qbc<0x55>(a);                      \
      const float g_ = qbc<0xAA>(a), o_ = qbc<0xFF>(a);                      \
      C0v = f_ * C0v + i_ * g_; h0_ = o_ * tanh_(C0v); }                     \
    { const float pre = ACC[1] + BIAS + (X1);                                \
      const float a = cA + cB * rcp_(1.f + exp2_(cC * pre));                 \
      const float i_ = qbc<0x00>(a), f_ = qbc<0x55>(a);                      \
      const float g_ = qbc<0xAA>(a), o_ = qbc<0xFF>(a);                      \
      C1v = f_ * C1v + i_ * g_; h1_ = o_ * tanh_(C1v); }                     \
    { const float pre = ACC[2] + BIAS + (X2);                                \
      const float a = cA + cB * rcp_(1.f + exp2_(cC * pre));                 \
      const float i_ = qbc<0x00>(a), f_ = qbc<0x55>(a);                      \
      const float g_ = qbc<0xAA>(a), o_ = qbc<0xFF>(a);                      \
      C2v = f_ * C2v + i_ * g_; h2_ = o_ * tanh_(C2v); }                     \
    { const float pre = ACC[3] + BIAS + (X3);                                \
      const float a = cA + cB * rcp_(1.f + exp2_(cC * pre));                 \
      const float i_ = qbc<0x00>(a), f_ = qbc<0x55>(a);                      \
      const float g_ = qbc<0xAA>(a), o_ = qbc<0xFF>(a);                      \
      C3v = f_ * C3v + i_ * g_; h3_ = o_ * tanh_(C3v); }                     \
    const float t01 = gs0 ? h1_ : h0_;                                       \
    const float t23 = gs0 ? h3_ : h2_;                                       \
    const float hsel = gs1 ? t23 : t01;                                      \
    const unsigned short hh = bf16_rne(hsel);                                \
    const unsigned short hl = bf16_rne(hsel - bf16f(hh));                    \
    (PH)[wb * 72 + (WN)] = hh;                                               \
    (PL)[wb * 72 + (WN)] = hl;                                               \
  }

  for (int t = 0; t < 512; ++t) {
    if ((t & 63) == 0) {  // stage next 64 timesteps of x
      __syncthreads();
      if (tid < 256) {
        const int sb = tid >> 4, st = (tid & 15) << 2;
        *(float4*)&xs[sb][st] =
            *(const float4*)&x[(size_t)(bbase + sb) * 512 + t + st];
      }
      __syncthreads();
    }
    const int rp = (t + 1) & 1, wp = t & 1, tm = t & 63;
    const unsigned short* h0hr = &H0h[rp][0][0];
    const unsigned short* h0lr = &H0l[rp][0][0];
    unsigned short* h0hw = &H0h[wp][0][0];
    unsigned short* h0lw = &H0l[wp][0][0];
    const unsigned short* h1hr = &H1h[rp][0][0];
    const unsigned short* h1lr = &H1l[rp][0][0];
    unsigned short* h1hw = &H1h[wp][0][0];
    unsigned short* h1lw = &H1l[wp][0][0];

    // ================= layer 0: G = h0_prev x Whh0' =================
    const short8 a0h_k0 = rdfrag(h0hr + arow * 72 + k0a, h0hr + arow * 72 + k0a + 16);
    const short8 a0l_k0 = rdfrag(h0lr + arow * 72 + k0a, h0lr + arow * 72 + k0a + 16);
    const short8 a0h_k1 = rdfrag(h0hr + arow * 72 + 32 + k0a, h0hr + arow * 72 + 48 + k0a);
    const short8 a0l_k1 = rdfrag(h0lr + arow * 72 + 32 + k0a, h0lr + arow * 72 + 48 + k0a);
    f32x4 acc0 = {0.f, 0.f, 0.f, 0.f};
    f32x4 acc1 = {0.f, 0.f, 0.f, 0.f};
    acc0 = mfma16(a0l_k0, W0h0_T0, acc0);
    acc0 = mfma16(a0h_k0, W0l0_T0, acc0);
    acc0 = mfma16(a0h_k0, W0h0_T0, acc0);
    acc0 = mfma16(a0l_k1, W0h1_T0, acc0);
    acc0 = mfma16(a0h_k1, W0l1_T0, acc0);
    acc0 = mfma16(a0h_k1, W0h1_T0, acc0);
    acc1 = mfma16(a0l_k0, W0h0_T1, acc1);
    acc1 = mfma16(a0h_k0, W0l0_T1, acc1);
    acc1 = mfma16(a0h_k0, W0h0_T1, acc1);
    acc1 = mfma16(a0l_k1, W0h1_T1, acc1);
    acc1 = mfma16(a0h_k1, W0l1_T1, acc1);
    acc1 = mfma16(a0h_k1, W0h1_T1, acc1);

    const float xv0 = xs[4 * lg + 0][tm];
    const float xv1 = xs[4 * lg + 1][tm];
    const float xv2 = xs[4 * lg + 2][tm];
    const float xv3 = xs[4 * lg + 3][tm];

    FIN(acc0, bias0_T0, xv0 * wx_T0, xv1 * wx_T0, xv2 * wx_T0, xv3 * wx_T0,
        c0_T0_0, c0_T0_1, c0_T0_2, c0_T0_3, h0hw, h0lw, u_T0)
    FIN(acc1, bias0_T1, xv0 * wx_T1, xv1 * wx_T1, xv2 * wx_T1, xv3 * wx_T1,
        c0_T1_0, c0_T1_1, c0_T1_2, c0_T1_3, h0hw, h0lw, u_T1)
    __syncthreads();  // h0[t] ready

    // ===== layer 1: G = h0[t] x Wih1' + h1_prev x Whh1' =====
    const short8 a1h_k0 = rdfrag(h0hw + arow * 72 + k0a, h0hw + arow * 72 + k0a + 16);
    const short8 a1l_k0 = rdfrag(h0lw + arow * 72 + k0a, h0lw + arow * 72 + k0a + 16);
    const short8 a1h_k1 = rdfrag(h0hw + arow * 72 + 32 + k0a, h0hw + arow * 72 + 48 + k0a);
    const short8 a1l_k1 = rdfrag(h0lw + arow * 72 + 32 + k0a, h0lw + arow * 72 + 48 + k0a);
    const short8 a1h_k2 = rdfrag(h1hr + arow * 72 + k0a, h1hr + arow * 72 + k0a + 16);
    const short8 a1l_k2 = rdfrag(h1lr + arow * 72 + k0a, h1lr + arow * 72 + k0a + 16);
    const short8 a1h_k3 = rdfrag(h1hr + arow * 72 + 32 + k0a, h1hr + arow * 72 + 48 + k0a);
    const short8 a1l_k3 = rdfrag(h1lr + arow * 72 + 32 + k0a, h1lr + arow * 72 + 48 + k0a);
    f32x4 bcc0 = {0.f, 0.f, 0.f, 0.f};
    f32x4 bcc1 = {0.f, 0.f, 0.f, 0.f};
    bcc0 = mfma16(a1l_k0, WIh0_T0, bcc0);
    bcc0 = mfma16(a1h_k0, WIl0_T0, bcc0);
    bcc0 = mfma16(a1h_k0, WIh0_T0, bcc0);
    bcc0 = mfma16(a1l_k1, WIh1_T0, bcc0);
    bcc0 = mfma16(a1h_k1, WIl1_T0, bcc0);
    bcc0 = mfma16(a1h_k1, WIh1_T0, bcc0);
    bcc0 = mfma16(a1l_k2, WHh0_T0, bcc0);
    bcc0 = mfma16(a1h_k2, WHl0_T0, bcc0);
    bcc0 = mfma16(a1h_k2, WHh0_T0, bcc0);
    bcc0 = mfma16(a1l_k3, WHh1_T0, bcc0);
    bcc0 = mfma16(a1h_k3, WHl1_T0, bcc0);
    bcc0 = mfma16(a1h_k3, WHh1_T0, bcc0);
    bcc1 = mfma16(a1l_k0, WIh0_T1, bcc1);
    bcc1 = mfma16(a1h_k0, WIl0_T1, bcc1);
    bcc1 = mfma16(a1h_k0, WIh0_T1, bcc1);
    bcc1 = mfma16(a1l_k1, WIh1_T1, bcc1);
    bcc1 = mfma16(a1h_k1, WIl1_T1, bcc1);
    bcc1 = mfma16(a1h_k1, WIh1_T1, bcc1);
    bcc1 = mfma16(a1l_k2, WHh0_T1, bcc1);
    bcc1 = mfma16(a1h_k2, WHl0_T1, bcc1);
    bcc1 = mfma16(a1h_k2, WHh0_T1, bcc1);
    bcc1 = mfma16(a1l_k3, WHh1_T1, bcc1);
    bcc1 = mfma16(a1h_k3, WHl1_T1, bcc1);
    bcc1 = mfma16(a1h_k3, WHh1_T1, bcc1);

    FIN(bcc0, bias1_T0, 0.f, 0.f, 0.f, 0.f,
        c1_T0_0, c1_T0_1, c1_T0_2, c1_T0_3, h1hw, h1lw, u_T0)
    FIN(bcc1, bias1_T1, 0.f, 0.f, 0.f, 0.f,
        c1_T1_0, c1_T1_1, c1_T1_2, c1_T1_3, h1hw, h1lw, u_T1)
    __syncthreads();  // h1[t] ready; also guards next step's WAR
  }

  // ---- FC head: out[b] = fc_b + sum_j fcW[j] * h1_last[b][j] ----
  if (tid < 16) {
    float s = fcb[0];
    for (int j = 0; j < 50; ++j)
      s += fcW[j] * (bf16f(H1h[1][tid][j]) + bf16f(H1l[1][tid][j]));  // t=511 -> wp=1
    out[bbase + tid] = s;
  }
}

extern "C" void kernel_launch(void* const* d_in, const int* in_sizes, int n_in,
                              void* d_out, int out_size, void* d_ws, size_t ws_size,
                              hipStream_t stream) {
  const float* x    = (const float*)d_in[0];
  const float* Wih0 = (const float*)d_in[1];
  const float* Whh0 = (const float*)d_in[2];
  const float* bih0 = (const float*)d_in[3];
  const float* bhh0 = (const float*)d_in[4];
  const float* Wih1 = (const float*)d_in[5];
  const float* Whh1 = (const float*)d_in[6];
  const float* bih1 = (const float*)d_in[7];
  const float* bhh1 = (const float*)d_in[8];
  const float* fcW  = (const float*)d_in[9];
  const float* fcb  = (const float*)d_in[10];
  float* out = (float*)d_out;

  const int B = out_size;          // 4096
  const int blocks = B / 16;       // 256
  lstm2_kernel<<<dim3(blocks), dim3(512), 0, stream>>>(
      x, Wih0, Whh0, bih0, bhh0, Wih1, Whh1, bih1, bhh1, fcW, fcb, out);
}

// Round 9
// 684.144 us; speedup vs baseline: 47.2031x; 1.6440x over previous
//
#include <hip/hip_runtime.h>

// 2-layer LSTM (B=4096, T=512, H=50) + FC head.
// R9 vs R8 (1.125 ms, VALU 65% / MFMA 22% / 1e8 bank conflicts):
//  (1) h planes re-laid-out [kt][hh][s][batch][4] -> A-frag ds_read_b64 at
//      8*lane+const: coalesced, zero conflicts, one addr reg + immediates.
//  (2) FIN via 4x4 DPP quad transpose: each lane owns ONE (batch,unit)
//      c-update (was 4x redundant); act constants compile-time per gate.
//  (3) Wave specialization: waves 0-3 = layer0[t], waves 4-7 = layer1[t-1]
//      (software pipeline). ONE barrier/step (was 2). L1 skips t=0; extra
//      epilogue step computes h1[511]. Barrier sequences mirrored exactly.
//  (4) t-unroll x2 -> all parities compile-time.
// Math identical to R8 (bf16 hi/lo split, 3 mfma/product) -> absmax ~0.

typedef __attribute__((ext_vector_type(8))) short short8;
typedef __attribute__((ext_vector_type(4))) float f32x4;

#define LOG2E 1.44269504088896340736f

__device__ __forceinline__ unsigned short bf16_rne(float f) {
  unsigned int u = __float_as_uint(f);
  u += 0x7FFFu + ((u >> 16) & 1u);
  return (unsigned short)(u >> 16);
}
__device__ __forceinline__ float bf16f(unsigned short h) {
  return __uint_as_float(((unsigned int)h) << 16);
}
template <int CTRL>
__device__ __forceinline__ float dppf(float v) {
  return __int_as_float(
      __builtin_amdgcn_mov_dpp(__float_as_int(v), CTRL, 0xf, 0xf, true));
}
__device__ __forceinline__ float rcp_(float x) { return __builtin_amdgcn_rcpf(x); }
__device__ __forceinline__ float exp2_(float x) { return __builtin_amdgcn_exp2f(x); }
__device__ __forceinline__ float sigm(float x) {
  return rcp_(1.f + exp2_(-LOG2E * x));
}
__device__ __forceinline__ float tanh_(float x) {
  return 1.f - 2.f * rcp_(1.f + exp2_(2.f * LOG2E * x));
}
__device__ __forceinline__ f32x4 mfma16(short8 a, short8 b, f32x4 c) {
  return __builtin_amdgcn_mfma_f32_16x16x32_bf16(a, b, c, 0, 0, 0);
}

union ABu { struct { uint2 a, b; } u; short8 v; };
__device__ __forceinline__ short8 rdfrag(const unsigned short* p0,
                                         const unsigned short* p1) {
  ABu t;
  t.u.a = *(const uint2*)p0;
  t.u.b = *(const uint2*)p1;
  return t.v;
}

// B-fragment (hi & lo) of W (50x50 logical, gate-major rows) for column
// (n,gate); k = kbase + 16*(e>>2) + 4*lg + (e&3). Same mapping as R8.
__device__ __forceinline__ void loadB(const float* __restrict__ W, int n,
                                      int gate, int kbase, int lg,
                                      short8& h8, short8& l8) {
#pragma unroll
  for (int e = 0; e < 8; ++e) {
    const int k = kbase + 16 * (e >> 2) + 4 * lg + (e & 3);
    const bool v = (n < 50) && (k < 50);
    const float w = v ? W[(gate * 50 + n) * 50 + k] : 0.f;
    const unsigned short hb = bf16_rne(w);
    const unsigned short lb = bf16_rne(w - bf16f(hb));
    h8[e] = (short)hb;
    l8[e] = (short)lb;
  }
}

#define TILES(X) X(0) X(1) X(2) X(3)

// 4x4 quad transpose over (gate-lane q) x (acc index): 8 dpp + 8 cndmask.
// Stage1 (xor1): r_i' = ((q^i)&1) ? dpp_xor1(r_{i^1}) : r_i
// Stage2 (xor2): r_i''= ((q^i)&2) ? dpp_xor2(r'_{i^2}) : r'_i
#define TRSP(r0, r1, r2, r3)                                   \
  {                                                            \
    const float t0 = dppf<0xB1>(r1), t1 = dppf<0xB1>(r0);      \
    const float t2 = dppf<0xB1>(r3), t3 = dppf<0xB1>(r2);      \
    r0 = o1 ? t0 : r0; r1 = o1 ? r1 : t1;                      \
    r2 = o1 ? t2 : r2; r3 = o1 ? r3 : t3;                      \
    const float s0 = dppf<0x4E>(r2), s1 = dppf<0x4E>(r3);      \
    const float s2 = dppf<0x4E>(r0), s3 = dppf<0x4E>(r1);      \
    r0 = o2 ? s0 : r0; r1 = o2 ? s1 : r1;                      \
    r2 = o2 ? r2 : s2; r3 = o2 ? r3 : s3;                      \
  }

__global__ __launch_bounds__(512) void lstm2_kernel(
    const float* __restrict__ x,
    const float* __restrict__ Wih0, const float* __restrict__ Whh0,
    const float* __restrict__ bih0, const float* __restrict__ bhh0,
    const float* __restrict__ Wih1, const float* __restrict__ Whh1,
    const float* __restrict__ bih1, const float* __restrict__ bhh1,
    const float* __restrict__ fcW, const float* __restrict__ fcb,
    float* __restrict__ out) {
  const int tid = threadIdx.x;
  const int lane = tid & 63;
  const int wv = tid >> 6;      // wave 0..7
  const int wg = wv & 3;        // group index within layer-group
  const bool isL1 = wv >= 4;    // waves 4-7: layer 1
  const int lg = lane >> 4;     // 0..3 (k-slice / batch-group)
  const int l15 = lane & 15;
  const int q = lane & 3;       // gate column of this lane
  const int m = l15 >> 2;       // unit-sub within tile
  const int bbase = blockIdx.x * 16;

  // h planes: [parity][kt*512 + hh*256 + s*64 + b*4 + e] ushort,
  // where unit u = kt*32 + hh*16 + s*4 + e. A-frag read = 8*lane + const.
  __shared__ unsigned short H0h[2][1024], H0l[2][1024];
  __shared__ unsigned short H1h[2][1024], H1l[2][1024];
  __shared__ float xs2[64][16];    // x chunk: [t within chunk][batch]
  __shared__ float ldspad[16000];  // 62.5 KB pin -> 82.5 KB total, 1 blk/CU

  ((volatile float*)ldspad)[tid] = 0.f;

  for (int i = tid; i < 1024; i += 512) {  // zero all planes, both parities
    ((unsigned int*)H0h)[i] = 0u; ((unsigned int*)H0l)[i] = 0u;
    ((unsigned int*)H1h)[i] = 0u; ((unsigned int*)H1l)[i] = 0u;
  }

  const int lane4 = lane * 4;  // ushort index of this lane's A-frag slot
  const bool o1 = (q & 1) != 0, o2 = (q & 2) != 0;
  const int bown = 4 * lg + q;  // batch owned after transpose

#define WOFF(u) (((u) >> 5 << 9) + ((((u) >> 4) & 1) << 8) + \
                 ((((u) >> 2) & 3) << 6) + (bown << 2) + ((u) & 3))

#define STAGE(c)                                                        \
  {                                                                     \
    const int b_ = tid >> 4, fg_ = tid & 15;                            \
    const float4 v_ = *(const float4*)&x[(size_t)(bbase + b_) * 512 +   \
                                         (c) * 64 + 4 * fg_];           \
    xs2[4 * fg_ + 0][b_] = v_.x; xs2[4 * fg_ + 1][b_] = v_.y;           \
    xs2[4 * fg_ + 2][b_] = v_.z; xs2[4 * fg_ + 3][b_] = v_.w;           \
  }

  if (!isL1) {
    // ================= LAYER-0 WAVES =================
#define DECL0(T) short8 W0h0_##T, W0l0_##T, W0h1_##T, W0l1_##T;  \
    float bias0_##T, wx_##T; float c0_##T = 0.f; int woff_##T;
    TILES(DECL0)
#define LOAD0(T)                                                     \
    { const int u = 16 * wg + 4 * T + m;                             \
      loadB(Whh0, u, q, 0, lg, W0h0_##T, W0l0_##T);                  \
      loadB(Whh0, u, q, 32, lg, W0h1_##T, W0l1_##T);                 \
      const bool v = u < 50;                                         \
      bias0_##T = v ? (bih0[q * 50 + u] + bhh0[q * 50 + u]) : 0.f;   \
      wx_##T = v ? Wih0[q * 50 + u] : 0.f;                           \
      woff_##T = WOFF(u); }
    TILES(LOAD0)

#define L0TILE(T, WP)                                                \
    { f32x4 acc = {0.f, 0.f, 0.f, 0.f};                              \
      acc = mfma16(al0, W0h0_##T, acc);                              \
      acc = mfma16(ah0, W0l0_##T, acc);                              \
      acc = mfma16(ah0, W0h0_##T, acc);                              \
      acc = mfma16(al1, W0h1_##T, acc);                              \
      acc = mfma16(ah1, W0l1_##T, acc);                              \
      acc = mfma16(ah1, W0h1_##T, acc);                              \
      float p0 = acc[0] + bias0_##T + xv.x * wx_##T;                 \
      float p1 = acc[1] + bias0_##T + xv.y * wx_##T;                 \
      float p2 = acc[2] + bias0_##T + xv.z * wx_##T;                 \
      float p3 = acc[3] + bias0_##T + xv.w * wx_##T;                 \
      TRSP(p0, p1, p2, p3)                                           \
      const float i_ = sigm(p0), f_ = sigm(p1);                      \
      const float g_ = tanh_(p2), o_ = sigm(p3);                     \
      const float c = f_ * c0_##T + i_ * g_; c0_##T = c;             \
      const float h = o_ * tanh_(c);                                 \
      const unsigned short hh = bf16_rne(h);                         \
      const unsigned short hl = bf16_rne(h - bf16f(hh));             \
      H0h[WP][woff_##T] = hh; H0l[WP][woff_##T] = hl; }

#define L0STEP(RP, WP, tm)                                           \
    { const short8 ah0 = rdfrag(&H0h[RP][lane4], &H0h[RP][lane4 + 256]); \
      const short8 al0 = rdfrag(&H0l[RP][lane4], &H0l[RP][lane4 + 256]); \
      const short8 ah1 = rdfrag(&H0h[RP][512 + lane4], &H0h[RP][768 + lane4]); \
      const short8 al1 = rdfrag(&H0l[RP][512 + lane4], &H0l[RP][768 + lane4]); \
      const float4 xv = *(const float4*)&xs2[tm][4 * lg];            \
      L0TILE(0, WP) L0TILE(1, WP) L0TILE(2, WP) L0TILE(3, WP) }

    STAGE(0) __syncthreads();
    L0STEP(1, 0, 0) __syncthreads();  // tt=0: read zeros(parity1), write p0
    for (int it = 0; it < 255; ++it) {
      const int todd = 2 * it + 1;
      L0STEP(0, 1, (todd & 63)) __syncthreads();
      const int tev = todd + 1;
      if ((tev & 63) == 0) { STAGE(tev >> 6) __syncthreads(); }
      L0STEP(1, 0, (tev & 63)) __syncthreads();
    }
    L0STEP(0, 1, 63) __syncthreads();  // tt=511
    __syncthreads();                   // matches L1 epilogue barrier
  } else {
    // ================= LAYER-1 WAVES =================
#define DECL1(T) short8 WIh0_##T, WIl0_##T, WIh1_##T, WIl1_##T,      \
    WHh0_##T, WHl0_##T, WHh1_##T, WHl1_##T;                          \
    float bias1_##T; float c1_##T = 0.f; int woff_##T;
    TILES(DECL1)
#define LOAD1(T)                                                     \
    { const int u = 16 * wg + 4 * T + m;                             \
      loadB(Wih1, u, q, 0, lg, WIh0_##T, WIl0_##T);                  \
      loadB(Wih1, u, q, 32, lg, WIh1_##T, WIl1_##T);                 \
      loadB(Whh1, u, q, 0, lg, WHh0_##T, WHl0_##T);                  \
      loadB(Whh1, u, q, 32, lg, WHh1_##T, WHl1_##T);                 \
      const bool v = u < 50;                                         \
      bias1_##T = v ? (bih1[q * 50 + u] + bhh1[q * 50 + u]) : 0.f;   \
      woff_##T = WOFF(u); }
    TILES(LOAD1)

#define L1TILE(T, W1)                                                \
    { f32x4 acc = {0.f, 0.f, 0.f, 0.f};                              \
      acc = mfma16(bl0, WIh0_##T, acc);                              \
      acc = mfma16(bh0, WIl0_##T, acc);                              \
      acc = mfma16(bh0, WIh0_##T, acc);                              \
      acc = mfma16(bl1, WIh1_##T, acc);                              \
      acc = mfma16(bh1, WIl1_##T, acc);                              \
      acc = mfma16(bh1, WIh1_##T, acc);                              \
      acc = mfma16(cl0, WHh0_##T, acc);                              \
      acc = mfma16(ch0, WHl0_##T, acc);                              \
      acc = mfma16(ch0, WHh0_##T, acc);                              \
      acc = mfma16(cl1, WHh1_##T, acc);                              \
      acc = mfma16(ch1, WHl1_##T, acc);                              \
      acc = mfma16(ch1, WHh1_##T, acc);                              \
      float p0 = acc[0] + bias1_##T;                                 \
      float p1 = acc[1] + bias1_##T;                                 \
      float p2 = acc[2] + bias1_##T;                                 \
      float p3 = acc[3] + bias1_##T;                                 \
      TRSP(p0, p1, p2, p3)                                           \
      const float i_ = sigm(p0), f_ = sigm(p1);                      \
      const float g_ = tanh_(p2), o_ = sigm(p3);                     \
      const float c = f_ * c1_##T + i_ * g_; c1_##T = c;             \
      const float h = o_ * tanh_(c);                                 \
      const unsigned short hh = bf16_rne(h);                         \
      const unsigned short hl = bf16_rne(h - bf16f(hh));             \
      H1h[W1][woff_##T] = hh; H1l[W1][woff_##T] = hl; }

#define L1STEP(P0, R1, W1)                                               \
    { const short8 bh0 = rdfrag(&H0h[P0][lane4], &H0h[P0][lane4 + 256]); \
      const short8 bl0 = rdfrag(&H0l[P0][lane4], &H0l[P0][lane4 + 256]); \
      const short8 bh1 = rdfrag(&H0h[P0][512 + lane4], &H0h[P0][768 + lane4]); \
      const short8 bl1 = rdfrag(&H0l[P0][512 + lane4], &H0l[P0][768 + lane4]); \
      const short8 ch0 = rdfrag(&H1h[R1][lane4], &H1h[R1][lane4 + 256]); \
      const short8 cl0 = rdfrag(&H1l[R1][lane4], &H1l[R1][lane4 + 256]); \
      const short8 ch1 = rdfrag(&H1h[R1][512 + lane4], &H1h[R1][768 + lane4]); \
      const short8 cl1 = rdfrag(&H1l[R1][512 + lane4], &H1l[R1][768 + lane4]); \
      L1TILE(0, W1) L1TILE(1, W1) L1TILE(2, W1) L1TILE(3, W1) }

    __syncthreads(); __syncthreads();  // mirror peel barriers (no compute, tt=0 skip)
    for (int it = 0; it < 255; ++it) {
      // tt odd: h0[tt-1]=p0, h1[tt-2]=p1, write h1[tt-1]=p0
      L1STEP(0, 1, 0) __syncthreads();
      if (((2 * it + 2) & 63) == 0) __syncthreads();  // mirror stage barrier
      // tt even: h0[tt-1]=p1, h1[tt-2]=p0, write h1[tt-1]=p1
      L1STEP(1, 0, 1) __syncthreads();
    }
    L1STEP(0, 1, 0) __syncthreads();  // tt=511 -> h1[510]
    L1STEP(1, 0, 1) __syncthreads();  // epilogue -> h1[511] (parity 1)
  }

  // ---- FC head: out[b] = fc_b + sum_j fcW[j] * h1[511][b][j] ----
  if (tid < 16) {
    float s = fcb[0];
    for (int j = 0; j < 50; ++j) {
      const int idx = ((j >> 5) << 9) + (((j >> 4) & 1) << 8) +
                      (((j >> 2) & 3) << 6) + (tid << 2) + (j & 3);
      s += fcW[j] * (bf16f(H1h[1][idx]) + bf16f(H1l[1][idx]));
    }
    out[bbase + tid] = s;
  }
}

extern "C" void kernel_launch(void* const* d_in, const int* in_sizes, int n_in,
                              void* d_out, int out_size, void* d_ws, size_t ws_size,
                              hipStream_t stream) {
  const float* x    = (const float*)d_in[0];
  const float* Wih0 = (const float*)d_in[1];
  const float* Whh0 = (const float*)d_in[2];
  const float* bih0 = (const float*)d_in[3];
  const float* bhh0 = (const float*)d_in[4];
  const float* Wih1 = (const float*)d_in[5];
  const float* Whh1 = (const float*)d_in[6];
  const float* bih1 = (const float*)d_in[7];
  const float* bhh1 = (const float*)d_in[8];
  const float* fcW  = (const float*)d_in[9];
  const float* fcb  = (const float*)d_in[10];
  float* out = (float*)d_out;

  const int B = out_size;          // 4096
  const int blocks = B / 16;       // 256
  lstm2_kernel<<<dim3(blocks), dim3(512), 0, stream>>>(
      x, Wih0, Whh0, bih0, bhh0, Wih1, Whh1, bih1, bhh1, fcW, fcb, out);
}